// Round 4
// baseline (365.993 us; speedup 1.0000x reference)
//
#include <hip/hip_runtime.h>

#define NN 100000
#define DD 128
#define EE 640000
#define NPAD 100352   // NN rounded up to 256
#define NCHUNK 391    // ceil(NN/256)

typedef __bf16 bf16x8 __attribute__((ext_vector_type(8)));
typedef float floatx4 __attribute__((ext_vector_type(4)));

union FragU { int4 i; bf16x8 b; unsigned short us[8]; };

__device__ __forceinline__ unsigned short f2bf(float f) {
    unsigned int u = __float_as_uint(f);
    u += 0x7FFF + ((u >> 16) & 1);   // RNE
    return (unsigned short)(u >> 16);
}

// ---------------------------------------------------------------------------
// pre_k (fat): blocks [0,2500) histogram deg; [2500,5700) x->bf16 into d_out;
// [5700,5732) W1/W2 -> bf16
// ---------------------------------------------------------------------------
#define HBLK 2500
#define XBLK 3200
__global__ __launch_bounds__(256) void pre_k(
    const int* __restrict__ ei, int* __restrict__ deg,
    const float4* __restrict__ x4, ushort4* __restrict__ xb4,
    const float4* __restrict__ W1, const float4* __restrict__ W2,
    ushort4* __restrict__ wb1, ushort4* __restrict__ wb2) {
    int bid = blockIdx.x;
    if (bid < HBLK) {
        int e = bid * 256 + threadIdx.x;     // EE == 2500*256
        atomicAdd(&deg[ei[EE + e]], 1);
    } else if (bid < HBLK + XBLK) {
        for (int i = (bid - HBLK) * 256 + threadIdx.x; i < NN * 32;
             i += XBLK * 256) {
            float4 v = x4[i];
            ushort4 u;
            u.x = f2bf(v.x); u.y = f2bf(v.y); u.z = f2bf(v.z); u.w = f2bf(v.w);
            xb4[i] = u;
        }
    } else {
        int wb = bid - HBLK - XBLK;          // 0..31
        const float4* src = (wb < 16) ? W1 : W2;
        ushort4* dst = (wb < 16) ? wb1 : wb2;
        int i = (wb & 15) * 256 + threadIdx.x;  // 4096 float4 per W
        float4 v = src[i];
        ushort4 u;
        u.x = f2bf(v.x); u.y = f2bf(v.y); u.z = f2bf(v.z); u.w = f2bf(v.w);
        dst[i] = u;
    }
}

// ---------------------------------------------------------------------------
// exclusive scan (3 kernels); scan2 also zeroes stats
// ---------------------------------------------------------------------------
__global__ __launch_bounds__(256) void scan1_k(const int* __restrict__ deg,
                                               int* __restrict__ cursor,
                                               int* __restrict__ chunkSums) {
    __shared__ int s[256];
    int t = threadIdx.x, g = blockIdx.x * 256 + t;
    int v = (g < NN) ? deg[g] : 0;
    s[t] = v;
    __syncthreads();
    for (int off = 1; off < 256; off <<= 1) {
        int u = (t >= off) ? s[t - off] : 0;
        __syncthreads();
        s[t] += u;
        __syncthreads();
    }
    if (g < NN) cursor[g] = s[t] - v;
    if (t == 255) chunkSums[blockIdx.x] = s[255];
}

__global__ __launch_bounds__(512) void scan2_k(int* __restrict__ chunkSums,
                                               int n, float* __restrict__ stats) {
    __shared__ int s[512];
    int t = threadIdx.x;
    stats[t] = 0.f;   // 512 floats, fold the memset here
    int v = (t < n) ? chunkSums[t] : 0;
    s[t] = v;
    __syncthreads();
    for (int off = 1; off < 512; off <<= 1) {
        int u = (t >= off) ? s[t - off] : 0;
        __syncthreads();
        s[t] += u;
        __syncthreads();
    }
    if (t < n) chunkSums[t] = s[t] - v;
}

__global__ __launch_bounds__(256) void scan3_k(int* __restrict__ cursor,
                                               const int* __restrict__ chunkSums) {
    int g = blockIdx.x * 256 + threadIdx.x;
    if (g < NN) cursor[g] += chunkSums[blockIdx.x];
}

__global__ __launch_bounds__(256) void esort_k(const int* __restrict__ ei,
                                               int* __restrict__ cursor,
                                               int* __restrict__ ssrc) {
    int e = blockIdx.x * 256 + threadIdx.x;
    if (e >= EE) return;
    int pos = atomicAdd(&cursor[ei[EE + e]], 1);
    ssrc[pos] = ei[e];
}

// ---------------------------------------------------------------------------
// aggregate: h[n] = bf16((1+eps)*x[n] + sum xb[src]); 16 lanes x 8 elems/node
// after esort, cursor[n] = end offset; start = end - deg
// ---------------------------------------------------------------------------
__global__ __launch_bounds__(256) void aggregate_k(
    const float* __restrict__ x, const unsigned short* __restrict__ xb,
    const int* __restrict__ ssrc, const int* __restrict__ cursor,
    const int* __restrict__ deg, const float* __restrict__ epsp,
    unsigned short* __restrict__ hout) {
    int tid = blockIdx.x * 256 + threadIdx.x;
    int node = tid >> 4, lane = tid & 15;
    if (node >= NN) return;
    int d = deg[node];
    int start = cursor[node] - d;
    float ef = 1.0f + epsp[0];

    const float4* xs = (const float4*)(x + node * 128 + lane * 8);
    float4 s0 = xs[0], s1 = xs[1];
    float acc[8] = {ef * s0.x, ef * s0.y, ef * s0.z, ef * s0.w,
                    ef * s1.x, ef * s1.y, ef * s1.z, ef * s1.w};

    for (int j = 0; j < d; ++j) {
        int s = ssrc[start + j];
        int4 raw = *(const int4*)(xb + s * 128 + lane * 8);
        unsigned int u0 = (unsigned int)raw.x, u1 = (unsigned int)raw.y;
        unsigned int u2 = (unsigned int)raw.z, u3 = (unsigned int)raw.w;
        acc[0] += __uint_as_float(u0 << 16);
        acc[1] += __uint_as_float(u0 & 0xffff0000u);
        acc[2] += __uint_as_float(u1 << 16);
        acc[3] += __uint_as_float(u1 & 0xffff0000u);
        acc[4] += __uint_as_float(u2 << 16);
        acc[5] += __uint_as_float(u2 & 0xffff0000u);
        acc[6] += __uint_as_float(u3 << 16);
        acc[7] += __uint_as_float(u3 & 0xffff0000u);
    }
    FragU o;
#pragma unroll
    for (int i = 0; i < 8; ++i) o.us[i] = f2bf(acc[i]);
    *(int4*)(hout + node * 128 + lane * 8) = o.i;
}

// ---------------------------------------------------------------------------
// LDS-free GEMM: A,B fragments loaded straight to registers.
// MODE 0: A = hA bf16.  MODE 1: A = relu(BN1(y)) built from y fp32 IN PLACE
// (each wave reads exactly the 32 rows it later writes; per-wave waitcnt
//  drains loads before stores — safe).
// y_out = A @ W^T + bias (fp32), stats_out[c] += colsum, [128+c] += colsumsq
// ---------------------------------------------------------------------------
template <int MODE>
__global__ __launch_bounds__(256) void gemm_k(
    const unsigned short* __restrict__ hA,     // MODE0 input
    float* y,                                  // MODE1 input AND output (no restrict!)
    const unsigned short* __restrict__ Wb, const float* __restrict__ bias,
    const float* __restrict__ stats_in, const float* __restrict__ g,
    const float* __restrict__ be, float* __restrict__ stats_out) {
    __shared__ float sc[128], sh[128];
    __shared__ float s_sum[128], s_sq[128];
    const int tid = threadIdx.x;
    if (tid < 128) { s_sum[tid] = 0.f; s_sq[tid] = 0.f; }
    if (MODE == 1 && tid < 128) {
        const float inv = 1.0f / (float)NN;
        float mean = stats_in[tid] * inv;
        float var = stats_in[128 + tid] * inv - mean * mean;
        float s = g[tid] * rsqrtf(var + 1e-5f);
        sc[tid] = s;
        sh[tid] = be[tid] - mean * s;
    }
    __syncthreads();

    const int rowBase = blockIdx.x * 128;
    const int l = tid & 63, w = tid >> 6;
    const int m = l & 15, q = l >> 4;

    floatx4 acc[2][8];
#pragma unroll
    for (int rt = 0; rt < 2; ++rt)
#pragma unroll
        for (int ct = 0; ct < 8; ++ct) acc[rt][ct] = (floatx4)0.0f;

#pragma unroll 1
    for (int kc = 0; kc < 4; ++kc) {
        const int k0 = kc * 32 + q * 8;
        bf16x8 a[2];
#pragma unroll
        for (int rt = 0; rt < 2; ++rt) {
            int rg = rowBase + w * 32 + rt * 16 + m;
            FragU u;
            if (MODE == 0) {
                u.i = (rg < NN) ? *(const int4*)(hA + rg * 128 + k0)
                                : make_int4(0, 0, 0, 0);
            } else {
                if (rg < NN) {
                    const float4* p = (const float4*)(y + rg * 128 + k0);
                    float4 v0 = p[0], v1 = p[1];
                    u.us[0] = f2bf(fmaxf(v0.x * sc[k0+0] + sh[k0+0], 0.f));
                    u.us[1] = f2bf(fmaxf(v0.y * sc[k0+1] + sh[k0+1], 0.f));
                    u.us[2] = f2bf(fmaxf(v0.z * sc[k0+2] + sh[k0+2], 0.f));
                    u.us[3] = f2bf(fmaxf(v0.w * sc[k0+3] + sh[k0+3], 0.f));
                    u.us[4] = f2bf(fmaxf(v1.x * sc[k0+4] + sh[k0+4], 0.f));
                    u.us[5] = f2bf(fmaxf(v1.y * sc[k0+5] + sh[k0+5], 0.f));
                    u.us[6] = f2bf(fmaxf(v1.z * sc[k0+6] + sh[k0+6], 0.f));
                    u.us[7] = f2bf(fmaxf(v1.w * sc[k0+7] + sh[k0+7], 0.f));
                } else {
                    u.i = make_int4(0, 0, 0, 0);
                }
            }
            a[rt] = u.b;
        }
#pragma unroll
        for (int ct = 0; ct < 8; ++ct) {
            bf16x8 b = *(const bf16x8*)(Wb + (ct * 16 + m) * 128 + k0);
            acc[0][ct] = __builtin_amdgcn_mfma_f32_16x16x32_bf16(a[0], b, acc[0][ct], 0, 0, 0);
            acc[1][ct] = __builtin_amdgcn_mfma_f32_16x16x32_bf16(a[1], b, acc[1][ct], 0, 0, 0);
        }
    }

    // epilogue: bias, store y, column stats (mask padding rows)
#pragma unroll
    for (int ct = 0; ct < 8; ++ct) {
        int col = ct * 16 + m;
        float bc = bias[col];
        float ps = 0.f, pq = 0.f;
#pragma unroll
        for (int rt = 0; rt < 2; ++rt) {
#pragma unroll
            for (int i = 0; i < 4; ++i) {
                int rg = rowBase + w * 32 + rt * 16 + q * 4 + i;
                if (rg < NN) {
                    float yv = acc[rt][ct][i] + bc;
                    y[rg * 128 + col] = yv;
                    ps += yv;
                    pq += yv * yv;
                }
            }
        }
        atomicAdd(&s_sum[col], ps);
        atomicAdd(&s_sq[col], pq);
    }
    __syncthreads();
    if (tid < 128) {
        unsafeAtomicAdd(&stats_out[tid], s_sum[tid]);
        unsafeAtomicAdd(&stats_out[128 + tid], s_sq[tid]);
    }
}

// ---------------------------------------------------------------------------
// final BN + ReLU in place on d_out (fp32)
// ---------------------------------------------------------------------------
__global__ __launch_bounds__(256) void bn_final_k(
    float* y, const float* __restrict__ stats,
    const float* __restrict__ g, const float* __restrict__ beta) {
    __shared__ __align__(16) float sc[128];
    __shared__ __align__(16) float sh[128];
    int t = threadIdx.x;
    if (t < 128) {
        const float inv = 1.0f / (float)NN;
        float mean = stats[t] * inv;
        float var = stats[128 + t] * inv - mean * mean;
        float s = g[t] * rsqrtf(var + 1e-5f);
        sc[t] = s;
        sh[t] = beta[t] - mean * s;
    }
    __syncthreads();
    const int total4 = NN * 32;
    float4* y4 = (float4*)y;
    for (int i = blockIdx.x * 256 + t; i < total4; i += gridDim.x * 256) {
        int c4 = i & 31;
        float4 v = y4[i];
        float4 s = ((const float4*)sc)[c4];
        float4 b = ((const float4*)sh)[c4];
        v.x = fmaxf(v.x * s.x + b.x, 0.f);
        v.y = fmaxf(v.y * s.y + b.y, 0.f);
        v.z = fmaxf(v.z * s.z + b.z, 0.f);
        v.w = fmaxf(v.w * s.w + b.w, 0.f);
        y4[i] = v;
    }
}

// ---------------------------------------------------------------------------
extern "C" void kernel_launch(void* const* d_in, const int* in_sizes, int n_in,
                              void* d_out, int out_size, void* d_ws, size_t ws_size,
                              hipStream_t stream) {
    const float* x   = (const float*)d_in[0];
    const int* ei    = (const int*)d_in[1];   // int64 in ref -> int32 from harness
    const float* eps = (const float*)d_in[2];
    const float* W1  = (const float*)d_in[3];
    const float* b1  = (const float*)d_in[4];
    const float* g1  = (const float*)d_in[5];
    const float* be1 = (const float*)d_in[6];
    const float* W2  = (const float*)d_in[7];
    const float* b2  = (const float*)d_in[8];
    const float* g2  = (const float*)d_in[9];
    const float* be2 = (const float*)d_in[10];
    float* out = (float*)d_out;

    // Workspace (~29 MB): CSR + h buffer + bf16 weights + stats.
    // xb (bf16 x) lives in the FIRST HALF OF d_out: dead before gemm1
    // overwrites d_out with y1.  y1/y2 in d_out; gemm2 + bn_final in place.
    int* deg        = (int*)d_ws;            // NPAD
    int* cursor     = deg + NPAD;            // NPAD
    int* chunkSums  = cursor + NPAD;         // 512
    int* ssrc       = chunkSums + 512;       // EE
    unsigned short* hbuf = (unsigned short*)(ssrc + EE);     // N*128 bf16
    unsigned short* wb1  = hbuf + (size_t)NN * DD;           // 16384
    unsigned short* wb2  = wb1 + 16384;                      // 16384
    float* stats    = (float*)(wb2 + 16384);                 // 512
    unsigned short* xb = (unsigned short*)d_out;             // N*128 bf16

    hipMemsetAsync(deg, 0, NPAD * sizeof(int), stream);

    pre_k<<<HBLK + XBLK + 32, 256, 0, stream>>>(
        ei, deg, (const float4*)x, (ushort4*)xb,
        (const float4*)W1, (const float4*)W2, (ushort4*)wb1, (ushort4*)wb2);
    scan1_k<<<NCHUNK, 256, 0, stream>>>(deg, cursor, chunkSums);
    scan2_k<<<1, 512, 0, stream>>>(chunkSums, NCHUNK, stats);
    scan3_k<<<NCHUNK, 256, 0, stream>>>(cursor, chunkSums);
    esort_k<<<(EE + 255) / 256, 256, 0, stream>>>(ei, cursor, ssrc);
    aggregate_k<<<(NN * 16 + 255) / 256, 256, 0, stream>>>(
        x, xb, ssrc, cursor, deg, eps, hbuf);

    const int gblocks = (NN + 127) / 128;  // 782
    gemm_k<0><<<gblocks, 256, 0, stream>>>(hbuf, out, wb1, b1,
                                           nullptr, nullptr, nullptr, stats);
    gemm_k<1><<<gblocks, 256, 0, stream>>>(nullptr, out, wb2, b2,
                                           stats, g1, be1, stats + 256);
    bn_final_k<<<4096, 256, 0, stream>>>(out, stats + 256, g2, be2);
}